// Round 3
// baseline (967.628 us; speedup 1.0000x reference)
//
#include <hip/hip_runtime.h>
#include <math.h>

// Problem constants (fixed by the reference)
constexpr int CB = 2, CS = 2048, CD = 1024, CH = 16, CHD = 64;
constexpr int CEMB = 1024;

typedef unsigned short ushort_t;
typedef __attribute__((ext_vector_type(8))) short short8;   // 8 bf16 = 4 VGPR
typedef __attribute__((ext_vector_type(4))) float f32x4;    // MFMA acc

// fp32 -> bf16 round-to-nearest-even (finite data only)
__device__ __forceinline__ ushort_t f2bf(float x) {
    unsigned int u = __builtin_bit_cast(unsigned int, x);
    u = u + 0x7fffu + ((u >> 16) & 1u);
    return (ushort_t)(u >> 16);
}
__device__ __forceinline__ float bf2f(ushort_t h) {
    unsigned int u = ((unsigned int)h) << 16;
    return __builtin_bit_cast(float, u);
}

// ===========================================================================
// Weight pre-pass: W[k][n] fp32 -> WT_hi[n][k], WT_lo[n][k] bf16 (split).
// 64x64 tile transpose through LDS. Runs once per launch (~10us).
// ===========================================================================
__global__ __launch_bounds__(256) void convert_wt(
    const float* __restrict__ W0, const float* __restrict__ W1,
    const float* __restrict__ W2, const float* __restrict__ W3,
    ushort_t* __restrict__ H0, ushort_t* __restrict__ L0,
    ushort_t* __restrict__ H1, ushort_t* __restrict__ L1,
    ushort_t* __restrict__ H2, ushort_t* __restrict__ L2,
    ushort_t* __restrict__ H3, ushort_t* __restrict__ L3) {
    const float* W;
    ushort_t* Hd;
    ushort_t* Ld;
    switch (blockIdx.z) {
        case 0: W = W0; Hd = H0; Ld = L0; break;
        case 1: W = W1; Hd = H1; Ld = L1; break;
        case 2: W = W2; Hd = H2; Ld = L2; break;
        default: W = W3; Hd = H3; Ld = L3; break;
    }
    const int n0 = blockIdx.x * 64, k0 = blockIdx.y * 64;
    __shared__ float Ls[64][65];
    const int t = threadIdx.x;
#pragma unroll
    for (int rep = 0; rep < 4; rep++) {
        const int r = rep * 16 + (t >> 4);   // k-local
        const int c4 = (t & 15) * 4;         // n-local
        *(float4*)&Ls[r][c4] = *(const float4*)&W[(size_t)(k0 + r) * CEMB + n0 + c4];
    }
    __syncthreads();
    const int n = t >> 2, kc = (t & 3) * 16;
#pragma unroll
    for (int c = 0; c < 2; c++) {
        union { ushort_t us[8]; uint4 v; } H, L;
#pragma unroll
        for (int j = 0; j < 8; j++) {
            const float x = Ls[kc + c * 8 + j][n];
            const ushort_t h = f2bf(x);
            H.us[j] = h;
            L.us[j] = f2bf(x - bf2f(h));
        }
        const size_t dst = (size_t)(n0 + n) * CEMB + k0 + kc + c * 8;
        *(uint4*)&Hd[dst] = H.v;
        *(uint4*)&Ld[dst] = L.v;
    }
}

// ===========================================================================
// Split-bf16 MFMA GEMM: C[M,N] = A[M,K] @ B[K,N], fp32 A/C, pre-split bf16 B
// in transposed [n][k] layout. 128x128 tile, BK=32, 4 waves (2x2), each wave
// 4x4 frags of mfma_f32_16x16x32_bf16. Three products per frag:
//   acc = Ahi*Bhi + Ahi*Blo + Alo*Bhi   (Alo*Blo ~2^-16 rel, dropped)
// LDS [row][32] bf16, 16B-chunk XOR swizzle chunk^((row>>1)&3): fragment
// ds_read_b128 lands 2-way max (free, m136).
// GATHER_A: A read from [b,h,s,d] (merged [b*s, h*64+d]).
// SCATTER_C: C written to [b,h,s,d].
// ===========================================================================
template <bool GATHER_A, bool SCATTER_C>
__device__ __forceinline__ void gemm_split_body(
    const float* __restrict__ A, const ushort_t* __restrict__ Bhi,
    const ushort_t* __restrict__ Blo, float* __restrict__ C,
    int M, int N, int K) {
    __shared__ ushort_t As_hi[128 * 32], As_lo[128 * 32];
    __shared__ ushort_t Bs_hi[128 * 32], Bs_lo[128 * 32];
    const int tid = threadIdx.x;
    const int row0 = blockIdx.y * 128, col0 = blockIdx.x * 128;
    const int w = tid >> 6, l = tid & 63, lr = l & 15, lg = l >> 4;
    const int wm = w >> 1, wn = w & 1;

    f32x4 acc[4][4];
#pragma unroll
    for (int i = 0; i < 4; i++)
#pragma unroll
        for (int j = 0; j < 4; j++) acc[i][j] = (f32x4)(0.f);

    const int st_r = tid >> 1;         // 0..127 (A-row / B-col)
    const int st_kh = (tid & 1) * 16;  // 0 or 16

    for (int k0 = 0; k0 < K; k0 += 32) {
        // ---- stage A: 16 fp32 -> split bf16, 2x 16B chunks to hi + lo ----
        {
            const int gm = row0 + st_r;
            const int gk = k0 + st_kh;
            const float* src;
            if (GATHER_A) {
                const int b_ = gm >> 11, s_ = gm & 2047;
                const int h_ = gk >> 6, d_ = gk & 63;
                src = &A[(((size_t)b_ * CH + h_) * CS + s_) * CHD + d_];
            } else {
                src = &A[(size_t)gm * K + gk];
            }
            float va[16];
#pragma unroll
            for (int r = 0; r < 4; r++)
                *(float4*)&va[r * 4] = *(const float4*)&src[r * 4];
#pragma unroll
            for (int c = 0; c < 2; c++) {
                union { ushort_t us[8]; uint4 v; } H, L;
#pragma unroll
                for (int j = 0; j < 8; j++) {
                    const float x = va[c * 8 + j];
                    const ushort_t h = f2bf(x);
                    H.us[j] = h;
                    L.us[j] = f2bf(x - bf2f(h));
                }
                const int chunk = (st_kh >> 3) + c;
                const int csw = chunk ^ ((st_r >> 1) & 3);
                *(uint4*)&As_hi[st_r * 32 + csw * 8] = H.v;
                *(uint4*)&As_lo[st_r * 32 + csw * 8] = L.v;
            }
        }
        // ---- stage B: copy pre-split bf16 [n][k] rows ----
        {
            const size_t base = (size_t)(col0 + st_r) * K + k0 + st_kh;
#pragma unroll
            for (int c = 0; c < 2; c++) {
                const uint4 hv = *(const uint4*)&Bhi[base + c * 8];
                const uint4 lv = *(const uint4*)&Blo[base + c * 8];
                const int chunk = (st_kh >> 3) + c;
                const int csw = chunk ^ ((st_r >> 1) & 3);
                *(uint4*)&Bs_hi[st_r * 32 + csw * 8] = hv;
                *(uint4*)&Bs_lo[st_r * 32 + csw * 8] = lv;
            }
        }
        __syncthreads();

        // ---- fragments: A[l&15][(l>>4)*8+i], B[(l>>4)*8+i][l&15] ----
        short8 ah[4], al[4], bh[4], bl[4];
#pragma unroll
        for (int i = 0; i < 4; i++) {
            const int r = wm * 64 + i * 16 + lr;
            const int cs = lg ^ ((r >> 1) & 3);
            ah[i] = *(const short8*)&As_hi[r * 32 + cs * 8];
            al[i] = *(const short8*)&As_lo[r * 32 + cs * 8];
        }
#pragma unroll
        for (int j = 0; j < 4; j++) {
            const int cc = wn * 64 + j * 16 + lr;
            const int cs = lg ^ ((cc >> 1) & 3);
            bh[j] = *(const short8*)&Bs_hi[cc * 32 + cs * 8];
            bl[j] = *(const short8*)&Bs_lo[cc * 32 + cs * 8];
        }
#pragma unroll
        for (int j = 0; j < 4; j++)
#pragma unroll
            for (int i = 0; i < 4; i++) {
                acc[i][j] = __builtin_amdgcn_mfma_f32_16x16x32_bf16(
                    al[i], bh[j], acc[i][j], 0, 0, 0);
                acc[i][j] = __builtin_amdgcn_mfma_f32_16x16x32_bf16(
                    ah[i], bl[j], acc[i][j], 0, 0, 0);
                acc[i][j] = __builtin_amdgcn_mfma_f32_16x16x32_bf16(
                    ah[i], bh[j], acc[i][j], 0, 0, 0);
            }
        __syncthreads();
    }

    // ---- epilogue: D col=l&15, row=(l>>4)*4+r (m89-verified) ----
#pragma unroll
    for (int i = 0; i < 4; i++)
#pragma unroll
        for (int j = 0; j < 4; j++) {
            const int cc = col0 + wn * 64 + j * 16 + lr;
#pragma unroll
            for (int r = 0; r < 4; r++) {
                const int cr = row0 + wm * 64 + i * 16 + lg * 4 + r;
                const float vv = acc[i][j][r];
                if (SCATTER_C) {
                    const int b_ = cr >> 11, s_ = cr & 2047;
                    const int h_ = cc >> 6, d_ = cc & 63;
                    C[(((size_t)b_ * CH + h_) * CS + s_) * CHD + d_] = vv;
                } else {
                    C[(size_t)cr * N + cc] = vv;
                }
            }
        }
}

// Fused Q/K/V projection (blockIdx.z picks the triple); scatter to [b,h,s,d].
__global__ __launch_bounds__(256, 2) void qkv_proj(
    const float* __restrict__ q, const float* __restrict__ k,
    const float* __restrict__ v,
    const ushort_t* __restrict__ hq, const ushort_t* __restrict__ lq,
    const ushort_t* __restrict__ hk, const ushort_t* __restrict__ lk,
    const ushort_t* __restrict__ hv, const ushort_t* __restrict__ lv,
    float* __restrict__ Qw, float* __restrict__ Kw, float* __restrict__ Vw) {
    const float* A;
    const ushort_t* Bh;
    const ushort_t* Bl;
    float* C;
    if (blockIdx.z == 0)      { A = q; Bh = hq; Bl = lq; C = Qw; }
    else if (blockIdx.z == 1) { A = k; Bh = hk; Bl = lk; C = Kw; }
    else                      { A = v; Bh = hv; Bl = lv; C = Vw; }
    gemm_split_body<false, true>(A, Bh, Bl, C, CB * CS, CEMB, CD);
}

// Output projection: gather A from [b,h,s,d] attn layout.
__global__ __launch_bounds__(256, 2) void out_proj(
    const float* __restrict__ attn, const ushort_t* __restrict__ ho,
    const ushort_t* __restrict__ lo_, float* __restrict__ out) {
    gemm_split_body<true, false>(attn, ho, lo_, out, CB * CS, CEMB, CEMB);
}

// ===========================================================================
// fp32 flash attention (causal optional). One block = 64 q-rows of one (b,h).
// [64][64] fp32 LDS tiles (4 x 16KB = 64KB total), 4-bit XOR swizzle:
// c4' = c4 ^ ((r>>2)&15) spreads the stride-256B rows across banks (2-way max
// on fragment reads). 256 threads as 16x16; thread (ty,tx) owns score rows
// ty*4..+3 x cols tx*4..+3 and O rows ty*4..+3 x dims tx*4..+3.
// ===========================================================================
__device__ __forceinline__ int sw4(int r, int c4) {
    return ((c4 ^ ((r >> 2) & 15)) << 2);
}

__global__ __launch_bounds__(256) void flash_attn(
    const float* __restrict__ Q, const float* __restrict__ K,
    const float* __restrict__ V, float* __restrict__ O,
    const int* __restrict__ maskedp) {
    __shared__ float Qs[64][64];
    __shared__ float Ks[64][64];
    __shared__ float Vs[64][64];
    __shared__ float Ps[64][64];
    const int tid = threadIdx.x;
    const int ty = tid >> 4, tx = tid & 15;
    const int qt = blockIdx.x;
    const int bh = blockIdx.y;
    const int q0 = qt * 64;
    const float* Qb = Q + (size_t)bh * CS * CHD;
    const float* Kb = K + (size_t)bh * CS * CHD;
    const float* Vb = V + (size_t)bh * CS * CHD;
    const int masked = maskedp[0];

    // load Q tile, pre-scaled by 1/sqrt(hd) = 0.125
#pragma unroll
    for (int rep = 0; rep < 4; rep++) {
        const int idx = rep * 256 + tid;
        const int r = idx >> 4, c4 = idx & 15;
        float4 v = *(const float4*)&Qb[(size_t)(q0 + r) * CHD + c4 * 4];
        v.x *= 0.125f; v.y *= 0.125f; v.z *= 0.125f; v.w *= 0.125f;
        *(float4*)&Qs[r][sw4(r, c4)] = v;
    }

    float m_i[4], l_i[4], o[4][4];
#pragma unroll
    for (int i = 0; i < 4; i++) {
        m_i[i] = -INFINITY;
        l_i[i] = 0.f;
#pragma unroll
        for (int j = 0; j < 4; j++) o[i][j] = 0.f;
    }

    const int nT = masked ? (qt + 1) : (CS / 64);
    for (int t = 0; t < nT; t++) {
        const int k0 = t * 64;
#pragma unroll
        for (int rep = 0; rep < 4; rep++) {
            const int idx = rep * 256 + tid;
            const int r = idx >> 4, c4 = idx & 15;
            *(float4*)&Ks[r][sw4(r, c4)] =
                *(const float4*)&Kb[(size_t)(k0 + r) * CHD + c4 * 4];
            *(float4*)&Vs[r][sw4(r, c4)] =
                *(const float4*)&Vb[(size_t)(k0 + r) * CHD + c4 * 4];
        }
        __syncthreads();

        // S = Q @ K^T (4x4 per thread)
        float sc[4][4];
#pragma unroll
        for (int i = 0; i < 4; i++)
#pragma unroll
            for (int j = 0; j < 4; j++) sc[i][j] = 0.f;
#pragma unroll
        for (int d4 = 0; d4 < 16; d4++) {
            float4 qv[4], kv[4];
#pragma unroll
            for (int i = 0; i < 4; i++)
                qv[i] = *(float4*)&Qs[ty * 4 + i][sw4(ty * 4 + i, d4)];
#pragma unroll
            for (int j = 0; j < 4; j++)
                kv[j] = *(float4*)&Ks[tx * 4 + j][sw4(tx * 4 + j, d4)];
#pragma unroll
            for (int i = 0; i < 4; i++)
#pragma unroll
                for (int j = 0; j < 4; j++) {
                    sc[i][j] = fmaf(qv[i].x, kv[j].x, sc[i][j]);
                    sc[i][j] = fmaf(qv[i].y, kv[j].y, sc[i][j]);
                    sc[i][j] = fmaf(qv[i].z, kv[j].z, sc[i][j]);
                    sc[i][j] = fmaf(qv[i].w, kv[j].w, sc[i][j]);
                }
        }

        // causal mask: only the diagonal tile needs it
        if (masked && t == qt) {
#pragma unroll
            for (int i = 0; i < 4; i++) {
                const int qg = q0 + ty * 4 + i;
#pragma unroll
                for (int j = 0; j < 4; j++) {
                    const int kg = k0 + tx * 4 + j;
                    if (kg > qg) sc[i][j] = -INFINITY;
                }
            }
        }

        // online softmax update (row stats across the 16-lane tx group)
#pragma unroll
        for (int i = 0; i < 4; i++) {
            float mt = fmaxf(fmaxf(sc[i][0], sc[i][1]), fmaxf(sc[i][2], sc[i][3]));
            mt = fmaxf(mt, __shfl_xor(mt, 1));
            mt = fmaxf(mt, __shfl_xor(mt, 2));
            mt = fmaxf(mt, __shfl_xor(mt, 4));
            mt = fmaxf(mt, __shfl_xor(mt, 8));
            const float mn = fmaxf(m_i[i], mt);
            const float corr = __expf(m_i[i] - mn);
            const float p0 = __expf(sc[i][0] - mn);
            const float p1 = __expf(sc[i][1] - mn);
            const float p2 = __expf(sc[i][2] - mn);
            const float p3 = __expf(sc[i][3] - mn);
            float rs = p0 + p1 + p2 + p3;
            rs += __shfl_xor(rs, 1);
            rs += __shfl_xor(rs, 2);
            rs += __shfl_xor(rs, 4);
            rs += __shfl_xor(rs, 8);
            l_i[i] = l_i[i] * corr + rs;
            m_i[i] = mn;
            o[i][0] *= corr; o[i][1] *= corr; o[i][2] *= corr; o[i][3] *= corr;
            *(float4*)&Ps[ty * 4 + i][sw4(ty * 4 + i, tx)] =
                make_float4(p0, p1, p2, p3);
        }
        __syncthreads();  // Ps visible to all

        // O += P @ V
#pragma unroll
        for (int k4 = 0; k4 < 16; k4++) {
            float4 pv[4];
#pragma unroll
            for (int i = 0; i < 4; i++)
                pv[i] = *(float4*)&Ps[ty * 4 + i][sw4(ty * 4 + i, k4)];
#pragma unroll
            for (int kk = 0; kk < 4; kk++) {
                const int vr = k4 * 4 + kk;
                const float4 vv = *(float4*)&Vs[vr][sw4(vr, tx)];
#pragma unroll
                for (int i = 0; i < 4; i++) {
                    const float pi = (&pv[i].x)[kk];
                    o[i][0] = fmaf(pi, vv.x, o[i][0]);
                    o[i][1] = fmaf(pi, vv.y, o[i][1]);
                    o[i][2] = fmaf(pi, vv.z, o[i][2]);
                    o[i][3] = fmaf(pi, vv.w, o[i][3]);
                }
            }
        }
        __syncthreads();  // protect Ks/Vs/Ps for next iteration
    }

    // normalize and write attn_out [b,h,s,hd]
#pragma unroll
    for (int i = 0; i < 4; i++) {
        const float inv = 1.0f / l_i[i];
        float4 v = make_float4(o[i][0] * inv, o[i][1] * inv,
                               o[i][2] * inv, o[i][3] * inv);
        *(float4*)&O[((size_t)bh * CS + q0 + ty * 4 + i) * CHD + tx * 4] = v;
    }
}

// ===========================================================================
extern "C" void kernel_launch(void* const* d_in, const int* in_sizes, int n_in,
                              void* d_out, int out_size, void* d_ws,
                              size_t ws_size, hipStream_t stream) {
    const float* q  = (const float*)d_in[0];
    const float* k  = (const float*)d_in[1];
    const float* v  = (const float*)d_in[2];
    const float* Wq = (const float*)d_in[3];
    const float* Wk = (const float*)d_in[4];
    const float* Wv = (const float*)d_in[5];
    const float* Wo = (const float*)d_in[6];
    const int* masked = (const int*)d_in[7];

    float* out  = (float*)d_out;                 // [B,S,1024]
    float* attn = out + (size_t)CB * CS * CEMB;  // [B,H,S,64] (2nd output)

    // workspace: Qw/Kw/Vw fp32 (48MB) + 8 split-weight bf16 buffers (16MB)
    const size_t NE = (size_t)CB * CS * CEMB;  // 4M elements
    float* Qw = (float*)d_ws;
    float* Kw = Qw + NE;
    float* Vw = Kw + NE;
    ushort_t* wb = (ushort_t*)(Vw + NE);
    const size_t WN = (size_t)CEMB * CEMB;  // 1M elements per weight
    ushort_t* hq = wb + 0 * WN;  ushort_t* lq = wb + 1 * WN;
    ushort_t* hk = wb + 2 * WN;  ushort_t* lk = wb + 3 * WN;
    ushort_t* hv = wb + 4 * WN;  ushort_t* lv = wb + 5 * WN;
    ushort_t* ho = wb + 6 * WN;  ushort_t* lo_ = wb + 7 * WN;

    const int M = CB * CS;  // 4096
    dim3 blk(256);

    // 1) weight transpose + split (runs every call; ~32MB traffic)
    convert_wt<<<dim3(16, 16, 4), blk, 0, stream>>>(
        Wq, Wk, Wv, Wo, hq, lq, hk, lk, hv, lv, ho, lo_);

    // 2) fused Q/K/V projections: grid (8, 32, 3) = 768 blocks
    qkv_proj<<<dim3(CEMB / 128, M / 128, 3), blk, 0, stream>>>(
        q, k, v, hq, lq, hk, lk, hv, lv, Qw, Kw, Vw);

    // 3) causal flash attention -> attn_out slot
    flash_attn<<<dim3(CS / 64, CB * CH), blk, 0, stream>>>(Qw, Kw, Vw, attn,
                                                           masked);

    // 4) output projection
    out_proj<<<dim3(CEMB / 128, M / 128), blk, 0, stream>>>(attn, ho, lo_, out);
}

// Round 4
// 423.954 us; speedup vs baseline: 2.2824x; 2.2824x over previous
//
#include <hip/hip_runtime.h>
#include <math.h>

// Problem constants (fixed by the reference)
constexpr int CB = 2, CS = 2048, CD = 1024, CH = 16, CHD = 64;
constexpr int CEMB = 1024;

typedef unsigned short ushort_t;
typedef __attribute__((ext_vector_type(8))) short short8;   // 8 bf16 = 4 VGPR
typedef __attribute__((ext_vector_type(4))) float f32x4;    // MFMA acc

// fp32 -> bf16 round-to-nearest-even (finite data only)
__device__ __forceinline__ ushort_t f2bf(float x) {
    unsigned int u = __builtin_bit_cast(unsigned int, x);
    u = u + 0x7fffu + ((u >> 16) & 1u);
    return (ushort_t)(u >> 16);
}
__device__ __forceinline__ float bf2f(ushort_t h) {
    unsigned int u = ((unsigned int)h) << 16;
    return __builtin_bit_cast(float, u);
}

// ===========================================================================
// Weight pre-pass: W[k][n] fp32 -> WT_hi[n][k], WT_lo[n][k] bf16 (split).
// ===========================================================================
__global__ __launch_bounds__(256) void convert_wt(
    const float* __restrict__ W0, const float* __restrict__ W1,
    const float* __restrict__ W2, const float* __restrict__ W3,
    ushort_t* __restrict__ H0, ushort_t* __restrict__ L0,
    ushort_t* __restrict__ H1, ushort_t* __restrict__ L1,
    ushort_t* __restrict__ H2, ushort_t* __restrict__ L2,
    ushort_t* __restrict__ H3, ushort_t* __restrict__ L3) {
    const float* W;
    ushort_t* Hd;
    ushort_t* Ld;
    switch (blockIdx.z) {
        case 0: W = W0; Hd = H0; Ld = L0; break;
        case 1: W = W1; Hd = H1; Ld = L1; break;
        case 2: W = W2; Hd = H2; Ld = L2; break;
        default: W = W3; Hd = H3; Ld = L3; break;
    }
    const int n0 = blockIdx.x * 64, k0 = blockIdx.y * 64;
    __shared__ float Ls[64][65];
    const int t = threadIdx.x;
#pragma unroll
    for (int rep = 0; rep < 4; rep++) {
        const int r = rep * 16 + (t >> 4);
        const int c4 = (t & 15) * 4;
        *(float4*)&Ls[r][c4] = *(const float4*)&W[(size_t)(k0 + r) * CEMB + n0 + c4];
    }
    __syncthreads();
    const int n = t >> 2, kc = (t & 3) * 16;
#pragma unroll
    for (int c = 0; c < 2; c++) {
        union { ushort_t us[8]; uint4 v; } H, L;
#pragma unroll
        for (int j = 0; j < 8; j++) {
            const float x = Ls[kc + c * 8 + j][n];
            const ushort_t h = f2bf(x);
            H.us[j] = h;
            L.us[j] = f2bf(x - bf2f(h));
        }
        const size_t dst = (size_t)(n0 + n) * CEMB + k0 + kc + c * 8;
        *(uint4*)&Hd[dst] = H.v;
        *(uint4*)&Ld[dst] = L.v;
    }
}

// ===========================================================================
// Split-bf16 MFMA GEMM: 128x128 tile, BK=32, 4 waves, 4x4 16x16x32 frags.
// Epilogue modes (runtime): 0 = fp32 row-major [M][N]
//                           1 = split bf16 scatter [b,h,s,d], pre-scaled
//                           2 = single bf16 scatter [b,h,d,s] (V transposed)
// ===========================================================================
template <bool GATHER_A>
__device__ __forceinline__ void gemm_split_body(
    const float* __restrict__ A, const ushort_t* __restrict__ Bhi,
    const ushort_t* __restrict__ Blo, float* __restrict__ Cf,
    ushort_t* __restrict__ C0, ushort_t* __restrict__ C1, float scale,
    int emode, int M, int N, int K) {
    __shared__ ushort_t As_hi[128 * 32], As_lo[128 * 32];
    __shared__ ushort_t Bs_hi[128 * 32], Bs_lo[128 * 32];
    const int tid = threadIdx.x;
    const int row0 = blockIdx.y * 128, col0 = blockIdx.x * 128;
    const int w = tid >> 6, l = tid & 63, lr = l & 15, lg = l >> 4;
    const int wm = w >> 1, wn = w & 1;

    f32x4 acc[4][4];
#pragma unroll
    for (int i = 0; i < 4; i++)
#pragma unroll
        for (int j = 0; j < 4; j++) acc[i][j] = (f32x4)(0.f);

    const int st_r = tid >> 1;
    const int st_kh = (tid & 1) * 16;

    for (int k0 = 0; k0 < K; k0 += 32) {
        {   // stage A: fp32 -> split bf16
            const int gm = row0 + st_r;
            const int gk = k0 + st_kh;
            const float* src;
            if (GATHER_A) {
                const int b_ = gm >> 11, s_ = gm & 2047;
                const int h_ = gk >> 6, d_ = gk & 63;
                src = &A[(((size_t)b_ * CH + h_) * CS + s_) * CHD + d_];
            } else {
                src = &A[(size_t)gm * K + gk];
            }
            float va[16];
#pragma unroll
            for (int r = 0; r < 4; r++)
                *(float4*)&va[r * 4] = *(const float4*)&src[r * 4];
#pragma unroll
            for (int c = 0; c < 2; c++) {
                union { ushort_t us[8]; uint4 v; } H, L;
#pragma unroll
                for (int j = 0; j < 8; j++) {
                    const float x = va[c * 8 + j];
                    const ushort_t h = f2bf(x);
                    H.us[j] = h;
                    L.us[j] = f2bf(x - bf2f(h));
                }
                const int chunk = (st_kh >> 3) + c;
                const int csw = chunk ^ ((st_r >> 1) & 3);
                *(uint4*)&As_hi[st_r * 32 + csw * 8] = H.v;
                *(uint4*)&As_lo[st_r * 32 + csw * 8] = L.v;
            }
        }
        {   // stage B: pre-split bf16 [n][k]
            const size_t base = (size_t)(col0 + st_r) * K + k0 + st_kh;
#pragma unroll
            for (int c = 0; c < 2; c++) {
                const uint4 hv = *(const uint4*)&Bhi[base + c * 8];
                const uint4 lv = *(const uint4*)&Blo[base + c * 8];
                const int chunk = (st_kh >> 3) + c;
                const int csw = chunk ^ ((st_r >> 1) & 3);
                *(uint4*)&Bs_hi[st_r * 32 + csw * 8] = hv;
                *(uint4*)&Bs_lo[st_r * 32 + csw * 8] = lv;
            }
        }
        __syncthreads();

        short8 ah[4], al[4], bh[4], bl[4];
#pragma unroll
        for (int i = 0; i < 4; i++) {
            const int r = wm * 64 + i * 16 + lr;
            const int cs = lg ^ ((r >> 1) & 3);
            ah[i] = *(const short8*)&As_hi[r * 32 + cs * 8];
            al[i] = *(const short8*)&As_lo[r * 32 + cs * 8];
        }
#pragma unroll
        for (int j = 0; j < 4; j++) {
            const int cc = wn * 64 + j * 16 + lr;
            const int cs = lg ^ ((cc >> 1) & 3);
            bh[j] = *(const short8*)&Bs_hi[cc * 32 + cs * 8];
            bl[j] = *(const short8*)&Bs_lo[cc * 32 + cs * 8];
        }
#pragma unroll
        for (int j = 0; j < 4; j++)
#pragma unroll
            for (int i = 0; i < 4; i++) {
                acc[i][j] = __builtin_amdgcn_mfma_f32_16x16x32_bf16(
                    al[i], bh[j], acc[i][j], 0, 0, 0);
                acc[i][j] = __builtin_amdgcn_mfma_f32_16x16x32_bf16(
                    ah[i], bl[j], acc[i][j], 0, 0, 0);
                acc[i][j] = __builtin_amdgcn_mfma_f32_16x16x32_bf16(
                    ah[i], bh[j], acc[i][j], 0, 0, 0);
            }
        __syncthreads();
    }

#pragma unroll
    for (int i = 0; i < 4; i++)
#pragma unroll
        for (int j = 0; j < 4; j++) {
            const int cc = col0 + wn * 64 + j * 16 + lr;
#pragma unroll
            for (int r = 0; r < 4; r++) {
                const int cr = row0 + wm * 64 + i * 16 + lg * 4 + r;
                const float vv = acc[i][j][r];
                if (emode == 0) {
                    Cf[(size_t)cr * N + cc] = vv;
                } else {
                    const int b_ = cr >> 11, s_ = cr & 2047;
                    const int h_ = cc >> 6, d_ = cc & 63;
                    if (emode == 1) {
                        const size_t idx =
                            (((size_t)b_ * CH + h_) * CS + s_) * CHD + d_;
                        const float x = vv * scale;
                        const ushort_t hb = f2bf(x);
                        C0[idx] = hb;
                        C1[idx] = f2bf(x - bf2f(hb));
                    } else {
                        C0[(((size_t)b_ * CH + h_) * CHD + d_) * CS + s_] =
                            f2bf(vv);
                    }
                }
            }
        }
}

__global__ __launch_bounds__(256, 2) void qkv_proj(
    const float* __restrict__ q, const float* __restrict__ k,
    const float* __restrict__ v,
    const ushort_t* __restrict__ hq, const ushort_t* __restrict__ lq,
    const ushort_t* __restrict__ hk, const ushort_t* __restrict__ lk,
    const ushort_t* __restrict__ hv, const ushort_t* __restrict__ lv,
    ushort_t* __restrict__ Qhi, ushort_t* __restrict__ Qlo,
    ushort_t* __restrict__ Khi, ushort_t* __restrict__ Klo,
    ushort_t* __restrict__ Vt) {
    const float* A;
    const ushort_t* Bh;
    const ushort_t* Bl;
    ushort_t* C0;
    ushort_t* C1 = nullptr;
    float scale = 1.0f;
    int emode;
    if (blockIdx.z == 0) {
        A = q; Bh = hq; Bl = lq; C0 = Qhi; C1 = Qlo; scale = 0.125f; emode = 1;
    } else if (blockIdx.z == 1) {
        A = k; Bh = hk; Bl = lk; C0 = Khi; C1 = Klo; emode = 1;
    } else {
        A = v; Bh = hv; Bl = lv; C0 = Vt; emode = 2;
    }
    gemm_split_body<false>(A, Bh, Bl, nullptr, C0, C1, scale, emode,
                           CB * CS, CEMB, CD);
}

__global__ __launch_bounds__(256, 2) void out_proj(
    const float* __restrict__ attn, const ushort_t* __restrict__ ho,
    const ushort_t* __restrict__ lo_, float* __restrict__ out) {
    gemm_split_body<true>(attn, ho, lo_, out, nullptr, nullptr, 1.0f, 0,
                          CB * CS, CEMB, CEMB);
}

// ===========================================================================
// MFMA flash attention. Grid (16, B*H). Block = 256 thr = 4 waves.
// Causal pairing: waves 0,1 own q-tile (31-j), waves 2,3 own q-tile j ->
// per-block compute = 33 tile-steps for every j (perfect balance, 2 blk/CU).
// Q in registers (split bf16, pre-scaled). K split / Vt / per-wave P in LDS,
// pitch 72 elems (144B = 9 quads, odd -> uniform bank-quad for b128 ops).
// QK^T = 3-product split MFMA (fp32-accurate scores); PV = plain bf16.
// ===========================================================================
constexpr int LP = 72;  // LDS row pitch in bf16 elems

__global__ __launch_bounds__(256, 2) void flash_mfma(
    const ushort_t* __restrict__ Qhi, const ushort_t* __restrict__ Qlo,
    const ushort_t* __restrict__ Khi, const ushort_t* __restrict__ Klo,
    const ushort_t* __restrict__ Vt, float* __restrict__ O,
    const int* __restrict__ maskedp) {
    __shared__ ushort_t Ks_hi[64 * LP];
    __shared__ ushort_t Ks_lo[64 * LP];
    __shared__ ushort_t Vs[64 * LP];
    __shared__ ushort_t Ps[4][32 * LP];
    const int tid = threadIdx.x;
    const int w = tid >> 6, l = tid & 63, lr = l & 15, lg = l >> 4;
    const int j = blockIdx.x;
    const int bh = blockIdx.y;
    const int masked = maskedp[0];
    const int myqt = (w < 2) ? (31 - j) : j;        // this wave's q-tile
    const int q0 = myqt * 64 + (w & 1) * 32;        // wave's first q-row
    const size_t bhoff = (size_t)bh * CS * CHD;

    // Q fragments in registers: [qf][dstep], rows q0+qf*16+lr, d=ds*32+lg*8
    short8 qh[2][2], ql[2][2];
#pragma unroll
    for (int qf = 0; qf < 2; qf++)
#pragma unroll
        for (int ds = 0; ds < 2; ds++) {
            const size_t off = bhoff + (size_t)(q0 + qf * 16 + lr) * CHD +
                               ds * 32 + lg * 8;
            qh[qf][ds] = *(const short8*)&Qhi[off];
            ql[qf][ds] = *(const short8*)&Qlo[off];
        }

    f32x4 Oacc[2][4];
    float m_i[2][4], l_i[2][4];
#pragma unroll
    for (int qf = 0; qf < 2; qf++)
#pragma unroll
        for (int d = 0; d < 4; d++) Oacc[qf][d] = (f32x4)(0.f);
#pragma unroll
    for (int qf = 0; qf < 2; qf++)
#pragma unroll
        for (int r = 0; r < 4; r++) { m_i[qf][r] = -INFINITY; l_i[qf][r] = 0.f; }

    const int tmax = masked ? (31 - j) : 31;   // loop bound (A-waves' need)
    const int tBmax = masked ? j : 31;         // B-waves stop after this

    const int st_r = tid >> 2;          // 0..63 staging row
    const int st_c = (tid & 3);         // chunk base

    for (int t = 0; t <= tmax; t++) {
        // ---- stage K(hi,lo) rows [k][d] and Vt rows [d][k] ----
#pragma unroll
        for (int p = 0; p < 2; p++) {
            const int c = st_c + p * 4;
            const size_t kgl = bhoff + (size_t)(t * 64 + st_r) * CHD + c * 8;
            *(uint4*)&Ks_hi[st_r * LP + c * 8] = *(const uint4*)&Khi[kgl];
            *(uint4*)&Ks_lo[st_r * LP + c * 8] = *(const uint4*)&Klo[kgl];
            const size_t vgl =
                ((size_t)bh * CHD + st_r) * CS + t * 64 + c * 8;
            *(uint4*)&Vs[st_r * LP + c * 8] = *(const uint4*)&Vt[vgl];
        }
        __syncthreads();

        const bool act = (w < 2) || (t <= tBmax);
        if (act) {
            // ---- S = Q @ K^T (split: ql*kh + qh*kl + qh*kh) ----
            f32x4 S[2][4];
#pragma unroll
            for (int qf = 0; qf < 2; qf++)
#pragma unroll
                for (int kf = 0; kf < 4; kf++) S[qf][kf] = (f32x4)(0.f);
#pragma unroll
            for (int ds = 0; ds < 2; ds++) {
                short8 kh[4], kl[4];
#pragma unroll
                for (int kf = 0; kf < 4; kf++) {
                    const int off = (kf * 16 + lr) * LP + ds * 32 + lg * 8;
                    kh[kf] = *(const short8*)&Ks_hi[off];
                    kl[kf] = *(const short8*)&Ks_lo[off];
                }
#pragma unroll
                for (int qf = 0; qf < 2; qf++)
#pragma unroll
                    for (int kf = 0; kf < 4; kf++) {
                        S[qf][kf] = __builtin_amdgcn_mfma_f32_16x16x32_bf16(
                            ql[qf][ds], kh[kf], S[qf][kf], 0, 0, 0);
                        S[qf][kf] = __builtin_amdgcn_mfma_f32_16x16x32_bf16(
                            qh[qf][ds], kl[kf], S[qf][kf], 0, 0, 0);
                        S[qf][kf] = __builtin_amdgcn_mfma_f32_16x16x32_bf16(
                            qh[qf][ds], kh[kf], S[qf][kf], 0, 0, 0);
                    }
            }

            // ---- causal mask (diagonal tile only) ----
            if (masked && t == myqt) {
#pragma unroll
                for (int qf = 0; qf < 2; qf++)
#pragma unroll
                    for (int kf = 0; kf < 4; kf++)
#pragma unroll
                        for (int r = 0; r < 4; r++) {
                            const int qg = q0 + qf * 16 + lg * 4 + r;
                            const int kg = t * 64 + kf * 16 + lr;
                            if (kg > qg) S[qf][kf][r] = -INFINITY;
                        }
            }

            // ---- online softmax (row stats over 16-lane lr group) ----
#pragma unroll
            for (int qf = 0; qf < 2; qf++)
#pragma unroll
                for (int r = 0; r < 4; r++) {
                    float mt = fmaxf(fmaxf(S[qf][0][r], S[qf][1][r]),
                                     fmaxf(S[qf][2][r], S[qf][3][r]));
                    mt = fmaxf(mt, __shfl_xor(mt, 1));
                    mt = fmaxf(mt, __shfl_xor(mt, 2));
                    mt = fmaxf(mt, __shfl_xor(mt, 4));
                    mt = fmaxf(mt, __shfl_xor(mt, 8));
                    const float mn = fmaxf(m_i[qf][r], mt);
                    const float corr = __expf(m_i[qf][r] - mn);
                    float rs = 0.f;
#pragma unroll
                    for (int kf = 0; kf < 4; kf++) {
                        const float p = __expf(S[qf][kf][r] - mn);
                        S[qf][kf][r] = p;
                        rs += p;
                    }
                    rs += __shfl_xor(rs, 1);
                    rs += __shfl_xor(rs, 2);
                    rs += __shfl_xor(rs, 4);
                    rs += __shfl_xor(rs, 8);
                    l_i[qf][r] = l_i[qf][r] * corr + rs;
                    m_i[qf][r] = mn;
#pragma unroll
                    for (int df = 0; df < 4; df++) Oacc[qf][df][r] *= corr;
                }

            // ---- P -> per-wave LDS (bf16, even/odd lane pack, b32) ----
#pragma unroll
            for (int qf = 0; qf < 2; qf++)
#pragma unroll
                for (int kf = 0; kf < 4; kf++)
#pragma unroll
                    for (int r = 0; r < 4; r++) {
                        const float v = S[qf][kf][r];
                        const float vo = __shfl_xor(v, 1);
                        const unsigned int pk =
                            (unsigned int)f2bf(v) |
                            ((unsigned int)f2bf(vo) << 16);
                        if (!(l & 1)) {
                            *(unsigned int*)&Ps[w][(qf * 16 + lg * 4 + r) * LP +
                                                   kf * 16 + lr] = pk;
                        }
                    }

            // ---- O += P @ V (per-wave private P: no barrier needed) ----
#pragma unroll
            for (int ks = 0; ks < 2; ks++) {
                short8 pa[2], vb[4];
#pragma unroll
                for (int qf = 0; qf < 2; qf++)
                    pa[qf] = *(const short8*)&Ps[w][(qf * 16 + lr) * LP +
                                                    ks * 32 + lg * 8];
#pragma unroll
                for (int df = 0; df < 4; df++)
                    vb[df] = *(const short8*)&Vs[(df * 16 + lr) * LP +
                                                 ks * 32 + lg * 8];
#pragma unroll
                for (int qf = 0; qf < 2; qf++)
#pragma unroll
                    for (int df = 0; df < 4; df++)
                        Oacc[qf][df] = __builtin_amdgcn_mfma_f32_16x16x32_bf16(
                            pa[qf], vb[df], Oacc[qf][df], 0, 0, 0);
            }
        }
        __syncthreads();  // protect K/V LDS for next tile
    }

    // ---- epilogue: normalize, write attn_out fp32 [b,h,s,d] ----
#pragma unroll
    for (int qf = 0; qf < 2; qf++)
#pragma unroll
        for (int r = 0; r < 4; r++) {
            const float inv = 1.0f / l_i[qf][r];
            const int qg = q0 + qf * 16 + lg * 4 + r;
#pragma unroll
            for (int df = 0; df < 4; df++) {
                O[bhoff + (size_t)qg * CHD + df * 16 + lr] =
                    Oacc[qf][df][r] * inv;
            }
        }
}

// ===========================================================================
extern "C" void kernel_launch(void* const* d_in, const int* in_sizes, int n_in,
                              void* d_out, int out_size, void* d_ws,
                              size_t ws_size, hipStream_t stream) {
    const float* q  = (const float*)d_in[0];
    const float* k  = (const float*)d_in[1];
    const float* v  = (const float*)d_in[2];
    const float* Wq = (const float*)d_in[3];
    const float* Wk = (const float*)d_in[4];
    const float* Wv = (const float*)d_in[5];
    const float* Wo = (const float*)d_in[6];
    const int* masked = (const int*)d_in[7];

    float* out  = (float*)d_out;                 // [B,S,1024]
    float* attn = out + (size_t)CB * CS * CEMB;  // [B,H,S,64] (2nd output)

    // workspace layout (bf16 buffers, all 16B aligned):
    const size_t NE = (size_t)CB * CS * CEMB;  // 4M elems per tensor
    ushort_t* wsb = (ushort_t*)d_ws;
    ushort_t* Qhi = wsb + 0 * NE;
    ushort_t* Qlo = wsb + 1 * NE;
    ushort_t* Khi = wsb + 2 * NE;
    ushort_t* Klo = wsb + 3 * NE;
    ushort_t* Vt  = wsb + 4 * NE;   // [b,h,d,s]
    ushort_t* wb  = wsb + 5 * NE;   // split weights: 8 x 1M
    const size_t WN = (size_t)CEMB * CEMB;
    ushort_t* hq = wb + 0 * WN;  ushort_t* lq = wb + 1 * WN;
    ushort_t* hk = wb + 2 * WN;  ushort_t* lk = wb + 3 * WN;
    ushort_t* hv = wb + 4 * WN;  ushort_t* lv = wb + 5 * WN;
    ushort_t* ho = wb + 6 * WN;  ushort_t* lo_ = wb + 7 * WN;

    const int M = CB * CS;  // 4096
    dim3 blk(256);

    convert_wt<<<dim3(16, 16, 4), blk, 0, stream>>>(
        Wq, Wk, Wv, Wo, hq, lq, hk, lk, hv, lv, ho, lo_);

    qkv_proj<<<dim3(CEMB / 128, M / 128, 3), blk, 0, stream>>>(
        q, k, v, hq, lq, hk, lk, hv, lv, Qhi, Qlo, Khi, Klo, Vt);

    flash_mfma<<<dim3(16, CB * CH), blk, 0, stream>>>(
        Qhi, Qlo, Khi, Klo, Vt, attn, masked);

    out_proj<<<dim3(CEMB / 128, M / 128), blk, 0, stream>>>(attn, ho, lo_, out);
}

// Round 6
// 378.683 us; speedup vs baseline: 2.5552x; 1.1195x over previous
//
#include <hip/hip_runtime.h>
#include <math.h>

// Problem constants (fixed by the reference)
constexpr int CB = 2, CS = 2048, CD = 1024, CH = 16, CHD = 64;
constexpr int CEMB = 1024;

typedef unsigned short ushort_t;
typedef __attribute__((ext_vector_type(8))) short short8;   // 8 bf16 = 4 VGPR
typedef __attribute__((ext_vector_type(4))) float f32x4;    // MFMA acc

// fp32 -> bf16 round-to-nearest-even (finite data only)
__device__ __forceinline__ ushort_t f2bf(float x) {
    unsigned int u = __builtin_bit_cast(unsigned int, x);
    u = u + 0x7fffu + ((u >> 16) & 1u);
    return (ushort_t)(u >> 16);
}
__device__ __forceinline__ float bf2f(ushort_t h) {
    unsigned int u = ((unsigned int)h) << 16;
    return __builtin_bit_cast(float, u);
}

// ===========================================================================
// Weight pre-pass: W[k][n] fp32 -> WT_hi[n][k], WT_lo[n][k] bf16 (split).
// ===========================================================================
__global__ __launch_bounds__(256) void convert_wt(
    const float* __restrict__ W0, const float* __restrict__ W1,
    const float* __restrict__ W2, const float* __restrict__ W3,
    ushort_t* __restrict__ H0, ushort_t* __restrict__ L0,
    ushort_t* __restrict__ H1, ushort_t* __restrict__ L1,
    ushort_t* __restrict__ H2, ushort_t* __restrict__ L2,
    ushort_t* __restrict__ H3, ushort_t* __restrict__ L3) {
    const float* W;
    ushort_t* Hd;
    ushort_t* Ld;
    switch (blockIdx.z) {
        case 0: W = W0; Hd = H0; Ld = L0; break;
        case 1: W = W1; Hd = H1; Ld = L1; break;
        case 2: W = W2; Hd = H2; Ld = L2; break;
        default: W = W3; Hd = H3; Ld = L3; break;
    }
    const int n0 = blockIdx.x * 64, k0 = blockIdx.y * 64;
    __shared__ float Ls[64][65];
    const int t = threadIdx.x;
#pragma unroll
    for (int rep = 0; rep < 4; rep++) {
        const int r = rep * 16 + (t >> 4);
        const int c4 = (t & 15) * 4;
        *(float4*)&Ls[r][c4] = *(const float4*)&W[(size_t)(k0 + r) * CEMB + n0 + c4];
    }
    __syncthreads();
    const int n = t >> 2, kc = (t & 3) * 16;
#pragma unroll
    for (int c = 0; c < 2; c++) {
        union { ushort_t us[8]; uint4 v; } H, L;
#pragma unroll
        for (int j = 0; j < 8; j++) {
            const float x = Ls[kc + c * 8 + j][n];
            const ushort_t h = f2bf(x);
            H.us[j] = h;
            L.us[j] = f2bf(x - bf2f(h));
        }
        const size_t dst = (size_t)(n0 + n) * CEMB + k0 + kc + c * 8;
        *(uint4*)&Hd[dst] = H.v;
        *(uint4*)&Ld[dst] = L.v;
    }
}

// ===========================================================================
// Split-bf16 MFMA GEMM: 128x128 tile, BK=32, 4 waves, 4x4 16x16x32 frags.
// Epilogue modes (runtime): 0 = fp32 row-major [M][N]
//                           1 = split bf16 scatter [b,h,s,d], pre-scaled
//                           2 = single bf16 scatter [b,h,d,s] (V transposed)
// ===========================================================================
template <bool GATHER_A>
__device__ __forceinline__ void gemm_split_body(
    const float* __restrict__ A, const ushort_t* __restrict__ Bhi,
    const ushort_t* __restrict__ Blo, float* __restrict__ Cf,
    ushort_t* __restrict__ C0, ushort_t* __restrict__ C1, float scale,
    int emode, int M, int N, int K) {
    __shared__ ushort_t As_hi[128 * 32], As_lo[128 * 32];
    __shared__ ushort_t Bs_hi[128 * 32], Bs_lo[128 * 32];
    const int tid = threadIdx.x;
    const int row0 = blockIdx.y * 128, col0 = blockIdx.x * 128;
    const int w = tid >> 6, l = tid & 63, lr = l & 15, lg = l >> 4;
    const int wm = w >> 1, wn = w & 1;

    f32x4 acc[4][4];
#pragma unroll
    for (int i = 0; i < 4; i++)
#pragma unroll
        for (int j = 0; j < 4; j++) acc[i][j] = (f32x4)(0.f);

    const int st_r = tid >> 1;
    const int st_kh = (tid & 1) * 16;

    for (int k0 = 0; k0 < K; k0 += 32) {
        {   // stage A: fp32 -> split bf16
            const int gm = row0 + st_r;
            const int gk = k0 + st_kh;
            const float* src;
            if (GATHER_A) {
                const int b_ = gm >> 11, s_ = gm & 2047;
                const int h_ = gk >> 6, d_ = gk & 63;
                src = &A[(((size_t)b_ * CH + h_) * CS + s_) * CHD + d_];
            } else {
                src = &A[(size_t)gm * K + gk];
            }
            float va[16];
#pragma unroll
            for (int r = 0; r < 4; r++)
                *(float4*)&va[r * 4] = *(const float4*)&src[r * 4];
#pragma unroll
            for (int c = 0; c < 2; c++) {
                union { ushort_t us[8]; uint4 v; } H, L;
#pragma unroll
                for (int j = 0; j < 8; j++) {
                    const float x = va[c * 8 + j];
                    const ushort_t h = f2bf(x);
                    H.us[j] = h;
                    L.us[j] = f2bf(x - bf2f(h));
                }
                const int chunk = (st_kh >> 3) + c;
                const int csw = chunk ^ ((st_r >> 1) & 3);
                *(uint4*)&As_hi[st_r * 32 + csw * 8] = H.v;
                *(uint4*)&As_lo[st_r * 32 + csw * 8] = L.v;
            }
        }
        {   // stage B: pre-split bf16 [n][k]
            const size_t base = (size_t)(col0 + st_r) * K + k0 + st_kh;
#pragma unroll
            for (int c = 0; c < 2; c++) {
                const uint4 hv = *(const uint4*)&Bhi[base + c * 8];
                const uint4 lv = *(const uint4*)&Blo[base + c * 8];
                const int chunk = (st_kh >> 3) + c;
                const int csw = chunk ^ ((st_r >> 1) & 3);
                *(uint4*)&Bs_hi[st_r * 32 + csw * 8] = hv;
                *(uint4*)&Bs_lo[st_r * 32 + csw * 8] = lv;
            }
        }
        __syncthreads();

        short8 ah[4], al[4], bh[4], bl[4];
#pragma unroll
        for (int i = 0; i < 4; i++) {
            const int r = wm * 64 + i * 16 + lr;
            const int cs = lg ^ ((r >> 1) & 3);
            ah[i] = *(const short8*)&As_hi[r * 32 + cs * 8];
            al[i] = *(const short8*)&As_lo[r * 32 + cs * 8];
        }
#pragma unroll
        for (int j = 0; j < 4; j++) {
            const int cc = wn * 64 + j * 16 + lr;
            const int cs = lg ^ ((cc >> 1) & 3);
            bh[j] = *(const short8*)&Bs_hi[cc * 32 + cs * 8];
            bl[j] = *(const short8*)&Bs_lo[cc * 32 + cs * 8];
        }
#pragma unroll
        for (int j = 0; j < 4; j++)
#pragma unroll
            for (int i = 0; i < 4; i++) {
                acc[i][j] = __builtin_amdgcn_mfma_f32_16x16x32_bf16(
                    al[i], bh[j], acc[i][j], 0, 0, 0);
                acc[i][j] = __builtin_amdgcn_mfma_f32_16x16x32_bf16(
                    ah[i], bl[j], acc[i][j], 0, 0, 0);
                acc[i][j] = __builtin_amdgcn_mfma_f32_16x16x32_bf16(
                    ah[i], bh[j], acc[i][j], 0, 0, 0);
            }
        __syncthreads();
    }

#pragma unroll
    for (int i = 0; i < 4; i++)
#pragma unroll
        for (int j = 0; j < 4; j++) {
            const int cc = col0 + wn * 64 + j * 16 + lr;
#pragma unroll
            for (int r = 0; r < 4; r++) {
                const int cr = row0 + wm * 64 + i * 16 + lg * 4 + r;
                const float vv = acc[i][j][r];
                if (emode == 0) {
                    Cf[(size_t)cr * N + cc] = vv;
                } else {
                    const int b_ = cr >> 11, s_ = cr & 2047;
                    const int h_ = cc >> 6, d_ = cc & 63;
                    if (emode == 1) {
                        const size_t idx =
                            (((size_t)b_ * CH + h_) * CS + s_) * CHD + d_;
                        const float x = vv * scale;
                        const ushort_t hb = f2bf(x);
                        C0[idx] = hb;
                        C1[idx] = f2bf(x - bf2f(hb));
                    } else {
                        C0[(((size_t)b_ * CH + h_) * CHD + d_) * CS + s_] =
                            f2bf(vv);
                    }
                }
            }
        }
}

__global__ __launch_bounds__(256, 2) void qkv_proj(
    const float* __restrict__ q, const float* __restrict__ k,
    const float* __restrict__ v,
    const ushort_t* __restrict__ hq, const ushort_t* __restrict__ lq,
    const ushort_t* __restrict__ hk, const ushort_t* __restrict__ lk,
    const ushort_t* __restrict__ hv, const ushort_t* __restrict__ lv,
    ushort_t* __restrict__ Qhi, ushort_t* __restrict__ Qlo,
    ushort_t* __restrict__ Khi, ushort_t* __restrict__ Klo,
    ushort_t* __restrict__ Vt) {
    const float* A;
    const ushort_t* Bh;
    const ushort_t* Bl;
    ushort_t* C0;
    ushort_t* C1 = nullptr;
    float scale = 1.0f;
    int emode;
    if (blockIdx.z == 0) {
        A = q; Bh = hq; Bl = lq; C0 = Qhi; C1 = Qlo; scale = 0.125f; emode = 1;
    } else if (blockIdx.z == 1) {
        A = k; Bh = hk; Bl = lk; C0 = Khi; C1 = Klo; emode = 1;
    } else {
        A = v; Bh = hv; Bl = lv; C0 = Vt; emode = 2;
    }
    gemm_split_body<false>(A, Bh, Bl, nullptr, C0, C1, scale, emode,
                           CB * CS, CEMB, CD);
}

__global__ __launch_bounds__(256, 2) void out_proj(
    const float* __restrict__ attn, const ushort_t* __restrict__ ho,
    const ushort_t* __restrict__ lo_, float* __restrict__ out) {
    gemm_split_body<true>(attn, ho, lo_, out, nullptr, nullptr, 1.0f, 0,
                          CB * CS, CEMB, CEMB);
}

// ===========================================================================
// MFMA flash attention, SWAPPED operands. Grid (16, B*H), 4 waves/block.
// Causal pairing: waves 0,1 own q-tile (31-j), waves 2,3 own q-tile j.
// S^T = mfma(K, Q): output col = q (lane&15), row = k. Each lane holds the
// full 64-k score row for ONE q per qf -> softmax reduce = in-reg + 2
// shuffles (vs 8/row before); P-pack = in-lane cvt (0 shuffles); PV as
// O^T = mfma(V^T, P^T) so corr/1/l are per-lane scalars (no redistribution).
// K/V next-tile global loads issued right after the post-staging barrier
// (T14-lite): latency hides under compute.
// ===========================================================================
constexpr int LP = 72;  // LDS row pitch in bf16 elems (144B = 9 quads, odd)

__global__ __launch_bounds__(256, 2) void flash_mfma(
    const ushort_t* __restrict__ Qhi, const ushort_t* __restrict__ Qlo,
    const ushort_t* __restrict__ Khi, const ushort_t* __restrict__ Klo,
    const ushort_t* __restrict__ Vt, float* __restrict__ O,
    const int* __restrict__ maskedp) {
    __shared__ ushort_t Ks_hi[64 * LP];
    __shared__ ushort_t Ks_lo[64 * LP];
    __shared__ ushort_t Vs[64 * LP];
    __shared__ ushort_t Ps[4][32 * LP];
    const int tid = threadIdx.x;
    const int w = tid >> 6, l = tid & 63, lr = l & 15, lg = l >> 4;
    const int j = blockIdx.x;
    const int bh = blockIdx.y;
    const int masked = maskedp[0];
    const int myqt = (w < 2) ? (31 - j) : j;
    const int q0 = myqt * 64 + (w & 1) * 32;
    const size_t bhoff = (size_t)bh * CS * CHD;

    // Q in registers; serves as the MFMA B-operand (B[kk][n] = Q[q][d]).
    short8 qh[2][2], ql[2][2];
#pragma unroll
    for (int qf = 0; qf < 2; qf++)
#pragma unroll
        for (int ds = 0; ds < 2; ds++) {
            const size_t off = bhoff + (size_t)(q0 + qf * 16 + lr) * CHD +
                               ds * 32 + lg * 8;
            qh[qf][ds] = *(const short8*)&Qhi[off];
            ql[qf][ds] = *(const short8*)&Qlo[off];
        }

    // O^T accumulators: Oacc[qf][df], lane: q = q0+qf*16+lr (col),
    // d = df*16+4*lg+r (row). m/l are per-lane scalars for that q.
    f32x4 Oacc[2][4];
    float m_i[2], l_i[2];
#pragma unroll
    for (int qf = 0; qf < 2; qf++) {
        m_i[qf] = -INFINITY;
        l_i[qf] = 0.f;
#pragma unroll
        for (int d = 0; d < 4; d++) Oacc[qf][d] = (f32x4)(0.f);
    }

    const int tmax = masked ? (31 - j) : 31;   // A-waves' bound (>= B's)
    const int tBmax = masked ? j : 31;         // B-waves stop after this

    const int st_r = tid >> 2;          // 0..63 staging row
    const int st_c = (tid & 3);         // chunk base

    // prefetch tile 0 into registers
    uint4 pk_hi[2], pk_lo[2], pv[2];
#pragma unroll
    for (int p = 0; p < 2; p++) {
        const int c = st_c + p * 4;
        const size_t kgl = bhoff + (size_t)(0 * 64 + st_r) * CHD + c * 8;
        pk_hi[p] = *(const uint4*)&Khi[kgl];
        pk_lo[p] = *(const uint4*)&Klo[kgl];
        const size_t vgl = ((size_t)bh * CHD + st_r) * CS + 0 * 64 + c * 8;
        pv[p] = *(const uint4*)&Vt[vgl];
    }

    for (int t = 0; t <= tmax; t++) {
        // ---- write prefetched K(hi,lo)/V^T regs to LDS ----
#pragma unroll
        for (int p = 0; p < 2; p++) {
            const int c = st_c + p * 4;
            *(uint4*)&Ks_hi[st_r * LP + c * 8] = pk_hi[p];
            *(uint4*)&Ks_lo[st_r * LP + c * 8] = pk_lo[p];
            *(uint4*)&Vs[st_r * LP + c * 8] = pv[p];
        }
        __syncthreads();

        // ---- issue next tile's loads; latency hides under compute ----
        if (t < tmax) {
#pragma unroll
            for (int p = 0; p < 2; p++) {
                const int c = st_c + p * 4;
                const size_t kgl =
                    bhoff + (size_t)((t + 1) * 64 + st_r) * CHD + c * 8;
                pk_hi[p] = *(const uint4*)&Khi[kgl];
                pk_lo[p] = *(const uint4*)&Klo[kgl];
                const size_t vgl =
                    ((size_t)bh * CHD + st_r) * CS + (t + 1) * 64 + c * 8;
                pv[p] = *(const uint4*)&Vt[vgl];
            }
        }

        const bool act = (w < 2) || (t <= tBmax);
        if (act) {
            // ---- S^T = K @ Q^T (split: Kh*Ql + Kl*Qh + Kh*Qh) ----
            // S[qf][kf]: lane holds k = t*64 + kf*16 + 4*lg + r, q = q0+qf*16+lr
            f32x4 S[2][4];
#pragma unroll
            for (int qf = 0; qf < 2; qf++)
#pragma unroll
                for (int kf = 0; kf < 4; kf++) S[qf][kf] = (f32x4)(0.f);
#pragma unroll
            for (int ds = 0; ds < 2; ds++) {
                short8 kh[4], kl[4];
#pragma unroll
                for (int kf = 0; kf < 4; kf++) {
                    const int off = (kf * 16 + lr) * LP + ds * 32 + lg * 8;
                    kh[kf] = *(const short8*)&Ks_hi[off];
                    kl[kf] = *(const short8*)&Ks_lo[off];
                }
#pragma unroll
                for (int qf = 0; qf < 2; qf++)
#pragma unroll
                    for (int kf = 0; kf < 4; kf++) {
                        S[qf][kf] = __builtin_amdgcn_mfma_f32_16x16x32_bf16(
                            kh[kf], ql[qf][ds], S[qf][kf], 0, 0, 0);
                        S[qf][kf] = __builtin_amdgcn_mfma_f32_16x16x32_bf16(
                            kl[kf], qh[qf][ds], S[qf][kf], 0, 0, 0);
                        S[qf][kf] = __builtin_amdgcn_mfma_f32_16x16x32_bf16(
                            kh[kf], qh[qf][ds], S[qf][kf], 0, 0, 0);
                    }
            }

            // ---- causal mask (diagonal tile only) ----
            if (masked && t == myqt) {
#pragma unroll
                for (int qf = 0; qf < 2; qf++) {
                    const int qg = q0 + qf * 16 + lr;
#pragma unroll
                    for (int kf = 0; kf < 4; kf++)
#pragma unroll
                        for (int r = 0; r < 4; r++) {
                            const int kg = t * 64 + kf * 16 + 4 * lg + r;
                            if (kg > qg) S[qf][kf][r] = -INFINITY;
                        }
                }
            }

            // ---- online softmax: in-reg over 16 + 2 shuffles across lg ----
#pragma unroll
            for (int qf = 0; qf < 2; qf++) {
                float mt = -INFINITY;
#pragma unroll
                for (int kf = 0; kf < 4; kf++)
#pragma unroll
                    for (int r = 0; r < 4; r++) mt = fmaxf(mt, S[qf][kf][r]);
                mt = fmaxf(mt, __shfl_xor(mt, 16));
                mt = fmaxf(mt, __shfl_xor(mt, 32));
                const float mn = fmaxf(m_i[qf], mt);
                const float corr = __expf(m_i[qf] - mn);
                float rs = 0.f;
#pragma unroll
                for (int kf = 0; kf < 4; kf++)
#pragma unroll
                    for (int r = 0; r < 4; r++) {
                        const float p = __expf(S[qf][kf][r] - mn);
                        S[qf][kf][r] = p;
                        rs += p;
                    }
                rs += __shfl_xor(rs, 16);
                rs += __shfl_xor(rs, 32);
                l_i[qf] = l_i[qf] * corr + rs;
                m_i[qf] = mn;
#pragma unroll
                for (int df = 0; df < 4; df++) Oacc[qf][df] *= corr;

                // ---- pack P (pairs along r are SAME-lane regs: 0 shuffles)
                // Ps[w] row = q-local (qf*16+lr), col = k-local
#pragma unroll
                for (int kf = 0; kf < 4; kf++)
#pragma unroll
                    for (int r2 = 0; r2 < 2; r2++) {
                        const unsigned int pk =
                            (unsigned int)f2bf(S[qf][kf][2 * r2]) |
                            ((unsigned int)f2bf(S[qf][kf][2 * r2 + 1]) << 16);
                        *(unsigned int*)&Ps[w][(qf * 16 + lr) * LP + kf * 16 +
                                               4 * lg + 2 * r2] = pk;
                    }
            }

            // ---- O^T += V^T @ P^T (per-wave private P, no barrier) ----
#pragma unroll
            for (int ks = 0; ks < 2; ks++) {
                short8 vb[4], pb[2];
#pragma unroll
                for (int df = 0; df < 4; df++)
                    vb[df] = *(const short8*)&Vs[(df * 16 + lr) * LP +
                                                 ks * 32 + lg * 8];
#pragma unroll
                for (int qf = 0; qf < 2; qf++)
                    pb[qf] = *(const short8*)&Ps[w][(qf * 16 + lr) * LP +
                                                    ks * 32 + lg * 8];
#pragma unroll
                for (int qf = 0; qf < 2; qf++)
#pragma unroll
                    for (int df = 0; df < 4; df++)
                        Oacc[qf][df] = __builtin_amdgcn_mfma_f32_16x16x32_bf16(
                            vb[df], pb[qf], Oacc[qf][df], 0, 0, 0);
            }
        }
        __syncthreads();  // protect K/V LDS for next tile
    }

    // ---- epilogue: normalize (per-lane l), write attn fp32 [b,h,s,d] ----
#pragma unroll
    for (int qf = 0; qf < 2; qf++) {
        const float inv = 1.0f / l_i[qf];
        const int qg = q0 + qf * 16 + lr;
#pragma unroll
        for (int df = 0; df < 4; df++)
#pragma unroll
            for (int r = 0; r < 4; r++) {
                O[bhoff + (size_t)qg * CHD + df * 16 + 4 * lg + r] =
                    Oacc[qf][df][r] * inv;
            }
    }
}

// ===========================================================================
extern "C" void kernel_launch(void* const* d_in, const int* in_sizes, int n_in,
                              void* d_out, int out_size, void* d_ws,
                              size_t ws_size, hipStream_t stream) {
    const float* q  = (const float*)d_in[0];
    const float* k  = (const float*)d_in[1];
    const float* v  = (const float*)d_in[2];
    const float* Wq = (const float*)d_in[3];
    const float* Wk = (const float*)d_in[4];
    const float* Wv = (const float*)d_in[5];
    const float* Wo = (const float*)d_in[6];
    const int* masked = (const int*)d_in[7];

    float* out  = (float*)d_out;                 // [B,S,1024]
    float* attn = out + (size_t)CB * CS * CEMB;  // [B,H,S,64] (2nd output)

    // workspace layout (bf16 buffers, all 16B aligned):
    const size_t NE = (size_t)CB * CS * CEMB;  // 4M elems per tensor
    ushort_t* wsb = (ushort_t*)d_ws;
    ushort_t* Qhi = wsb + 0 * NE;
    ushort_t* Qlo = wsb + 1 * NE;
    ushort_t* Khi = wsb + 2 * NE;
    ushort_t* Klo = wsb + 3 * NE;
    ushort_t* Vt  = wsb + 4 * NE;   // [b,h,d,s]
    ushort_t* wb  = wsb + 5 * NE;   // split weights: 8 x 1M
    const size_t WN = (size_t)CEMB * CEMB;
    ushort_t* hq = wb + 0 * WN;  ushort_t* lq = wb + 1 * WN;
    ushort_t* hk = wb + 2 * WN;  ushort_t* lk = wb + 3 * WN;
    ushort_t* hv = wb + 4 * WN;  ushort_t* lv = wb + 5 * WN;
    ushort_t* ho = wb + 6 * WN;  ushort_t* lo_ = wb + 7 * WN;

    const int M = CB * CS;  // 4096
    dim3 blk(256);

    convert_wt<<<dim3(16, 16, 4), blk, 0, stream>>>(
        Wq, Wk, Wv, Wo, hq, lq, hk, lk, hv, lv, ho, lo_);

    qkv_proj<<<dim3(CEMB / 128, M / 128, 3), blk, 0, stream>>>(
        q, k, v, hq, lq, hk, lk, hv, lv, Qhi, Qlo, Khi, Klo, Vt);

    flash_mfma<<<dim3(16, CB * CH), blk, 0, stream>>>(
        Qhi, Qlo, Khi, Klo, Vt, attn, masked);

    out_proj<<<dim3(CEMB / 128, M / 128), blk, 0, stream>>>(attn, ho, lo_, out);
}